// Round 20
// baseline (29.572 us; speedup 1.0000x reference)
//
#include <hip/hip_runtime.h>

// IIR filter bank: B=16, T=32768, F=30, order 6 (K=7).
// Overlap-and-discard chunking (WARM=128, 2x redundancy: lane outputs 128).
// R19: PAGE-SIZED WRITE BURSTS. R18 discriminator: -33% compute -> -6%
//   time; write BW pinned 2.56 TB/s (fill kernels: 6.3+). Suspect: HBM
//   page efficiency — R18 flush wrote each 1KB page as 4 x 256B pieces
//   ~5us apart. Fix: identical compute (31.5M steps, 2048 single-wave
//   blocks), flush ONCE with one instruction = one full row = 1KB
//   contiguous (64 lanes x float4), 30 instructions back-to-back.
//   ly [30][260] = 31.2KB -> 4 blocks/CU (R17: halved occupancy costs
//   ~7%; if writes are the wall, ~0). Discriminator: BW >=3.5 TB/s and
//   ~16us => page theory; flat ~24us => burst-shape-insensitive wall.

#define BB 16
#define TT 32768
#define FF 30
#define KK 7
#define ORD 6
#define LCH 128                // output samples per lane
#define WARM 128
#define CPB 2                  // lane groups (cl)
#define TSPAN (CPB * LCH)      // 256 samples per block
#define NBC (TT / TSPAN)       // 128 block-columns
#define YSTR 260               // ly row stride (1040B, 16B-aligned)
#define XTILE (WARM + TSPAN)   // 384 floats = 96 float4
#define BLK 64                 // ONE wave

// Transposed direct-form II step: 13 FMAs, no state shifting.
__device__ __forceinline__ float iir_step(float xv, float st[ORD],
                                          const float bcf[KK],
                                          const float acf[ORD]) {
    float y = fmaf(bcf[0], xv, st[0]);
#pragma unroll
    for (int j = 0; j < ORD - 1; ++j)
        st[j] = fmaf(-acf[j], y, fmaf(bcf[j + 1], xv, st[j + 1]));
    st[ORD - 1] = fmaf(-acf[ORD - 1], y, bcf[KK - 1] * xv);
    return y;
}

__global__ __launch_bounds__(BLK, 1) void iir_page_kernel(
    const float* __restrict__ x,    // [B][T]
    const float* __restrict__ bs,   // [F][K]
    const float* __restrict__ as_,  // [F][K]
    float* __restrict__ out)        // [B][F][T]
{
    __shared__ __align__(16) float ly[FF * YSTR];   // 31200 B
    __shared__ __align__(16) float lx[XTILE];       //  1536 B

    const int tid = threadIdx.x;
    const int b   = blockIdx.x / NBC;
    const int bc  = blockIdx.x % NBC;
    const int bt0 = bc * TSPAN;

    const int f  = tid % FF;        // lanes 0-29: cl=0, 30-59: cl=1
    const int cl = tid / FF;
    const bool active = tid < FF * CPB;

    // Lane-uniform-per-f coefficients.
    float bcf[KK], acf[ORD];
    {
        const int fc = active ? f : 0;
        const float inv_a0 = 1.0f / as_[fc * KK];
#pragma unroll
        for (int j = 0; j < KK; ++j) bcf[j] = bs[fc * KK + j] * inv_a0;
#pragma unroll
        for (int j = 0; j < ORD; ++j) acf[j] = as_[fc * KK + 1 + j] * inv_a0;
    }

    // Cooperative x stage: [bt0-128, bt0+256) = 96 float4; zero-fill t<0
    // (zero input keeps zero state -> exact head).
    {
        const float* __restrict__ xrow = x + b * TT;
#pragma unroll
        for (int i = 0; i < 2; ++i) {
            const int p = i * BLK + tid;
            if (p < XTILE / 4) {
                const int t = bt0 - WARM + 4 * p;
                float4 v = make_float4(0.f, 0.f, 0.f, 0.f);
                if (t >= 0) v = *reinterpret_cast<const float4*>(xrow + t);
                *reinterpret_cast<float4*>(lx + 4 * p) = v;
            }
        }
    }
    __syncthreads();   // single-wave block: cheap

    // Compute: lane (f, cl) warms 128 then outputs 128 samples into
    // ly[f][cl*128 ..): one ds_write_b128 per 4 samples.
    if (active) {
        const float4* lx4 = reinterpret_cast<const float4*>(lx);
        const int g0 = 32 * cl;     // window: lx4[g0 .. g0+64)
        float st[ORD];
#pragma unroll
        for (int j = 0; j < ORD; ++j) st[j] = 0.0f;

#pragma unroll
        for (int k = 0; k < 32; ++k) {      // warm-up, discard
            const float4 v = lx4[g0 + k];
            iir_step(v.x, st, bcf, acf);
            iir_step(v.y, st, bcf, acf);
            iir_step(v.z, st, bcf, acf);
            iir_step(v.w, st, bcf, acf);
        }
        float* lyc = ly + f * YSTR + cl * LCH;
#pragma unroll
        for (int k = 0; k < 32; ++k) {      // output 128 samples
            const float4 v = lx4[g0 + 32 + k];
            float4 y;
            y.x = iir_step(v.x, st, bcf, acf);
            y.y = iir_step(v.y, st, bcf, acf);
            y.z = iir_step(v.z, st, bcf, acf);
            y.w = iir_step(v.w, st, bcf, acf);
            *reinterpret_cast<float4*>(lyc + 4 * k) = y;
        }
    }
    __syncthreads();

    // Flush: 30 instructions, each = ONE ROW = 64 lanes x float4 = 1KB
    // fully contiguous -> each HBM page written in a single burst.
    // LDS read is 64 consecutive float4 of one row: sequential, clean.
    float* __restrict__ obase = out + b * FF * TT + bt0;
#pragma unroll
    for (int fr = 0; fr < FF; ++fr) {
        const float4 v =
            *reinterpret_cast<const float4*>(ly + fr * YSTR + 4 * tid);
        *reinterpret_cast<float4*>(obase + fr * TT + 4 * tid) = v;
    }
}

extern "C" void kernel_launch(void* const* d_in, const int* in_sizes, int n_in,
                              void* d_out, int out_size, void* d_ws,
                              size_t ws_size, hipStream_t stream) {
    const float* x   = (const float*)d_in[0];
    const float* bs  = (const float*)d_in[1];
    const float* as_ = (const float*)d_in[2];
    float* out = (float*)d_out;

    const int grid = BB * NBC;  // 2048 single-wave blocks
    hipLaunchKernelGGL(iir_page_kernel, dim3(grid), dim3(BLK), 0, stream,
                       x, bs, as_, out);
}